// Round 4
// baseline (409.053 us; speedup 1.0000x reference)
//
#include <hip/hip_runtime.h>
#include <math.h>

// Z = Q_F (D * (Q_F^T X Q_S)) Q_S^T  ==  per-column solve (I - g*lam_j*G) y_j = (X Q_S)_j ; Z = Y Q_S^T
// (I - aG)^-1 = prod_{j=0..4} (I + a^(2^j) G^(2^j))  (exact 31-term Neumann sum; rho <= 0.76)
// GEMMs: bf16 MFMA, A = hi+lo split (2 products), B = bf16 (2^-9 rel, OK vs 0.099 threshold).
//
// R4: R3's fused single-dispatch structure, but WITHOUT hipLaunchCooperativeKernel.
//  R3 evidence: absmax 4.97 == max|Z_ref| with Z memset to 0 -> kernel never ran
//  (cooperative launch is not graph-capturable; error unchecked by harness).
//  -> plain <<<1024,256>>> + hand-rolled single-use grid barriers in workspace.
//  Co-residency: grid 1024 = 256 CU x 4 blocks, __launch_bounds__(256,4), LDS 24 KB.
//  Barrier protocol (per use): syncthreads (vmcnt0: stores in L2) -> threadfence
//  (agent release: L2 wb) -> device-scope fetch_add + flag spin (AGENT scope) ->
//  threadfence (agent acquire: L2 inv) -> syncthreads. Flags zeroed per replay by
//  a 2 KB hipMemsetAsync (graph-capturable, ordered after harness ws poison-fill).
//  Phases: ph1 gemm1 (block 0: prep THEN tile 0 -> no 2x straggler) -> P1 slabs;
//  ph2 fused slab-reduce + Neumann solve -> Ybf hi/lo planes (MFMA-frag layout);
//  ph3 gemm2 A-frags register-direct from Ybf (LDS = B dbuf only, 1 barrier/step);
//  ph4 Z = sum of P2 slabs (1 float/thread).

typedef short short8 __attribute__((ext_vector_type(8)));
typedef float floatx16 __attribute__((ext_vector_type(16)));

#define KSPLIT 16
#define KCHUNK 256  // 4096 / KSPLIT, 4 steps of 64
constexpr int Mdim = 64;
constexpr int Ndim = 4096;
constexpr int TILE = Mdim * Ndim;  // 262144 floats = 1 MB
constexpr int NBLK = 1024;

__device__ inline ushort f2bf(float f) {
    uint u = __float_as_uint(f);
    u += 0x7fff + ((u >> 16) & 1);  // RNE
    return (ushort)(u >> 16);
}
__device__ inline float bf2f(ushort h) { return __uint_as_float(((uint)h) << 16); }

__device__ inline floatx16 mfma_bf16(short8 a, short8 b, floatx16 c) {
    return __builtin_amdgcn_mfma_f32_32x32x16_bf16(a, b, c, 0, 0, 0);
}

// LDS plane layout (bf16, 64x64 tile): elem (r,k) at r*64 + ((k>>3)^(r&7))*8 + (k&7).
union SharedU {
    struct { ushort Ah[4096], Al[4096], Bh[4096]; } g1;           // phase-1 gemm (24 KB)
    struct { ushort Bh[2][4096]; } g3;                            // phase-3 gemm (16 KB)
    struct { ushort planes[2][4096]; float red[256]; } p;         // prep (17 KB)
    struct { float Gs[64][66]; float T[64][5]; float Tp[4][64][4]; } s;  // solve (~22.3 KB)
};

// Workgroup barrier WITHOUT vmcnt drain: LDS visibility only needs lgkmcnt(0).
__device__ inline void barrier_nodrain() {
    asm volatile("s_waitcnt lgkmcnt(0)" ::: "memory");
    __builtin_amdgcn_s_barrier();
    __builtin_amdgcn_sched_barrier(0);
}

// Single-use grid barrier (slot idx). bar zeroed per replay by hipMemsetAsync.
__device__ inline void grid_barrier(uint* bar, int idx) {
    __syncthreads();  // drains vmcnt(0): all block stores acked into this XCD's L2
    if (threadIdx.x == 0) {
        __threadfence();  // agent release: L2 writeback
        uint* cnt  = bar + idx * 64;       // 256 B apart -> separate lines
        uint* flag = bar + idx * 64 + 32;
        uint old = __hip_atomic_fetch_add(cnt, 1u, __ATOMIC_ACQ_REL, __HIP_MEMORY_SCOPE_AGENT);
        if (old == (uint)NBLK - 1) {
            __hip_atomic_store(flag, 1u, __ATOMIC_RELEASE, __HIP_MEMORY_SCOPE_AGENT);
        } else {
            while (!__hip_atomic_load(flag, __ATOMIC_RELAXED, __HIP_MEMORY_SCOPE_AGENT))
                __builtin_amdgcn_s_sleep(1);
        }
        __threadfence();  // agent acquire: L2 invalidate (all dirty data already wb'd)
    }
    __syncthreads();
}

// ---------------- prep body: G, G^2, G^4, G^8, G^16 (one block) -------------
__device__ void prep_body(SharedU& sh, const float* __restrict__ F, float* __restrict__ Gout) {
    const int t = threadIdx.x;
    const int l = t & 63, w = t >> 6;
    const int tm = w & 1, tn = w >> 1;
    const int am = tm * 32 + (l & 31);
    const int bn = tn * 32 + (l & 31);
    const int lk = l >> 5;
    ushort* Ph = sh.p.planes[0];
    ushort* Pl = sh.p.planes[1];
    float* red = sh.p.red;

    {  // load F rows from global, scatter transposed into planes: P[c][k] = F[k][c]
        const int r = t >> 2, c0 = (t & 3) * 16;
#pragma unroll
        for (int q = 0; q < 4; ++q) {
            float4 v = *(const float4*)&F[r * 64 + c0 + 4 * q];
            float fa[4] = {v.x, v.y, v.z, v.w};
#pragma unroll
            for (int i = 0; i < 4; ++i) {
                int c = c0 + 4 * q + i;
                ushort h = f2bf(fa[i]);
                int idx = c * 64 + (((r >> 3) ^ (c & 7)) * 8) + (r & 7);
                Ph[idx] = h;
                Pl[idx] = f2bf(fa[i] - bf2f(h));
            }
        }
    }
    barrier_nodrain();
    floatx16 acc;
    for (int i = 0; i < 16; ++i) acc[i] = 0.f;
    for (int s16 = 0; s16 < 4; ++s16) {
        int gk = 2 * s16 + lk;
        int ai = am * 64 + ((gk ^ (am & 7)) * 8);
        int bi = bn * 64 + ((gk ^ (bn & 7)) * 8);
        short8 ah = *(const short8*)&Ph[ai];
        short8 al = *(const short8*)&Pl[ai];
        short8 bh = *(const short8*)&Ph[bi];
        short8 bl = *(const short8*)&Pl[bi];
        acc = mfma_bf16(ah, bh, acc);
        acc = mfma_bf16(al, bh, acc);
        acc = mfma_bf16(ah, bl, acc);
    }
    float ss = 0.f;
    for (int r = 0; r < 16; ++r) ss += acc[r] * acc[r];
    red[t] = ss;
    barrier_nodrain();
    for (int off = 128; off > 0; off >>= 1) {
        if (t < off) red[t] += red[t + off];
        barrier_nodrain();
    }
    const float inv = 1.0f / (sqrtf(red[0]) + 1e-12f);
    for (int r = 0; r < 16; ++r) {
        int row = (r & 3) + 8 * (r >> 2) + 4 * lk + tm * 32;
        int col = tn * 32 + (l & 31);
        float v = acc[r] * inv;
        Gout[row * 64 + col] = v;
        ushort h = f2bf(v);
        int idx = row * 64 + (((col >> 3) ^ (row & 7)) * 8 + (col & 7));
        Ph[idx] = h;
        Pl[idx] = f2bf(v - bf2f(h));
    }
    for (int j = 1; j < 5; ++j) {
        barrier_nodrain();
        floatx16 a2;
        for (int i = 0; i < 16; ++i) a2[i] = 0.f;
        for (int s16 = 0; s16 < 4; ++s16) {
            int gk = 2 * s16 + lk;
            int ai = am * 64 + ((gk ^ (am & 7)) * 8);
            int bi = bn * 64 + ((gk ^ (bn & 7)) * 8);
            short8 ah = *(const short8*)&Ph[ai];
            short8 al = *(const short8*)&Pl[ai];
            short8 bh = *(const short8*)&Ph[bi];
            short8 bl = *(const short8*)&Pl[bi];
            a2 = mfma_bf16(ah, bh, a2);
            a2 = mfma_bf16(al, bh, a2);
            a2 = mfma_bf16(ah, bl, a2);
        }
        barrier_nodrain();
        for (int r = 0; r < 16; ++r) {
            int row = (r & 3) + 8 * (r >> 2) + 4 * lk + tm * 32;
            int col = tn * 32 + (l & 31);
            float v = a2[r];
            Gout[j * 4096 + row * 64 + col] = v;
            ushort h = f2bf(v);
            int idx = row * 64 + (((col >> 3) ^ (row & 7)) * 8 + (col & 7));
            Ph[idx] = h;
            Pl[idx] = f2bf(v - bf2f(h));
        }
    }
}

// B-panel register load for one 64-k step.
template <bool TB>
__device__ inline void load_b(float4 (&dst)[4], const float* __restrict__ Bm,
                              int n0, int kk, int sr, int sj, int nq, int kr2) {
    if constexpr (TB) {
#pragma unroll
        for (int s = 0; s < 4; ++s)
            dst[s] = *(const float4*)&Bm[(size_t)(n0 + sr) * 4096 + kk + 4 * sj + 16 * s];
    } else {
#pragma unroll
        for (int s = 0; s < 2; ++s) {
            dst[2 * s + 0] = *(const float4*)&Bm[(size_t)(kk + kr2 + 32 * s) * 4096 + n0 + 4 * nq];
            dst[2 * s + 1] = *(const float4*)&Bm[(size_t)(kk + kr2 + 1 + 32 * s) * 4096 + n0 + 4 * nq];
        }
    }
}

// ---------------- phase-1 gemm: P1[ks] tile = X-chunk @ Qs-chunk ------------
__device__ void gemm_lds(SharedU& sh, const float* __restrict__ A, const float* __restrict__ Bm,
                         float* __restrict__ C, int tile, int t) {
    const int n0 = (tile & 63) * 64;
    const int ks = tile >> 6;
    const int kb = ks * KCHUNK;
    const int l = t & 63, w = t >> 6;
    const int tm = w & 1, tn = w >> 1;
    const int am = tm * 32 + (l & 31);
    const int bn = tn * 32 + (l & 31);
    const int lk = l >> 5;
    const int sr = t >> 2, sj = t & 3;          // row-staging map
    const int nq = t & 15, kr2 = 2 * (t >> 4);  // transpose-staging map

    floatx16 acc;
    for (int i = 0; i < 16; ++i) acc[i] = 0.f;

    float4 bbuf[4][4];
    load_b<false>(bbuf[0], Bm, n0, kb, sr, sj, nq, kr2);
    load_b<false>(bbuf[1], Bm, n0, kb + 64, sr, sj, nq, kr2);

#pragma unroll
    for (int step = 0; step < KCHUNK / 64; ++step) {
        const int k0 = kb + step * 64;
        // A loads for this step (L2-hot, short latency)
        float4 av[4];
#pragma unroll
        for (int s = 0; s < 4; ++s)
            av[s] = *(const float4*)&A[sr * 4096 + k0 + 4 * sj + 16 * s];
        // prefetch B two steps ahead
        if (step + 2 < KCHUNK / 64)
            load_b<false>(bbuf[step + 2], Bm, n0, k0 + 128, sr, sj, nq, kr2);
        barrier_nodrain();  // previous step's frag ds_reads done (lgkm only; vmem in flight)
        // stage B (hi only); counted vmcnt inserted at first bbuf[step] use
#pragma unroll
        for (int s = 0; s < 2; ++s) {
            int k = kr2 + 32 * s;
            float fa[4] = {bbuf[step][2 * s].x, bbuf[step][2 * s].y, bbuf[step][2 * s].z, bbuf[step][2 * s].w};
            float fb[4] = {bbuf[step][2 * s + 1].x, bbuf[step][2 * s + 1].y, bbuf[step][2 * s + 1].z, bbuf[step][2 * s + 1].w};
#pragma unroll
            for (int i = 0; i < 4; ++i) {
                int n = 4 * nq + i;
                int idx = n * 64 + (((k >> 3) ^ (n & 7)) * 8 + (k & 7));
                ushort2 hp2;
                hp2.x = f2bf(fa[i]);
                hp2.y = f2bf(fb[i]);
                *(ushort2*)&sh.g1.Bh[idx] = hp2;
            }
        }
        // stage A (hi + lo)
#pragma unroll
        for (int s = 0; s < 4; ++s) {
            int off = 4 * sj + 16 * s;
            int idx = sr * 64 + (((off >> 3) ^ (sr & 7)) * 8 + (off & 7));
            float fa[4] = {av[s].x, av[s].y, av[s].z, av[s].w};
            ushort4 h4, l4;
            ushort* hp = (ushort*)&h4; ushort* lp = (ushort*)&l4;
#pragma unroll
            for (int i = 0; i < 4; ++i) {
                ushort h = f2bf(fa[i]);
                hp[i] = h; lp[i] = f2bf(fa[i] - bf2f(h));
            }
            *(ushort4*)&sh.g1.Ah[idx] = h4;
            *(ushort4*)&sh.g1.Al[idx] = l4;
        }
        barrier_nodrain();  // staged planes visible to all waves
#pragma unroll
        for (int s16 = 0; s16 < 4; ++s16) {
            int gk = 2 * s16 + lk;
            int ai = am * 64 + ((gk ^ (am & 7)) * 8);
            int bi = bn * 64 + ((gk ^ (bn & 7)) * 8);
            short8 ah = *(const short8*)&sh.g1.Ah[ai];
            short8 al = *(const short8*)&sh.g1.Al[ai];
            short8 bh = *(const short8*)&sh.g1.Bh[bi];
            acc = mfma_bf16(ah, bh, acc);
            acc = mfma_bf16(al, bh, acc);
        }
    }
    float* Cp = C + (size_t)ks * TILE;
    const int colg = n0 + tn * 32 + (l & 31);
#pragma unroll
    for (int r = 0; r < 16; ++r) {
        int row = (r & 3) + 8 * (r >> 2) + 4 * lk + tm * 32;
        Cp[row * 4096 + colg] = acc[r];
    }
}

// ---------------- phase-3 gemm: P2[ks] tile = Ybf-chunk @ Qs^T-chunk --------
__device__ void gemm_direct(SharedU& sh, const ushort* __restrict__ Yh, const ushort* __restrict__ Yl,
                            const float* __restrict__ Bm, float* __restrict__ C, int tile, int t) {
    const int n0 = (tile & 63) * 64;
    const int ks = tile >> 6;
    const int kb = ks * KCHUNK;
    const int l = t & 63, w = t >> 6;
    const int tm = w & 1, tn = w >> 1;
    const int am = tm * 32 + (l & 31);
    const int bn = tn * 32 + (l & 31);
    const int lk = l >> 5;
    const int sr = t >> 2, sj = t & 3;  // row-staging map (TB=true)

    floatx16 acc;
    for (int i = 0; i < 16; ++i) acc[i] = 0.f;

    float4 bbuf[3][4];
    load_b<true>(bbuf[0], Bm, n0, kb, sr, sj, 0, 0);
    load_b<true>(bbuf[1], Bm, n0, kb + 64, sr, sj, 0, 0);

#pragma unroll
    for (int step = 0; step < KCHUNK / 64; ++step) {
        const int k0 = kb + step * 64;
        const int par = step & 1;
        const int slot = step % 3;
        // prefetch B two steps ahead into free ring slot
        if (step + 2 < KCHUNK / 64)
            load_b<true>(bbuf[(step + 2) % 3], Bm, n0, k0 + 128, sr, sj, 0, 0);
        // A frags direct from Ybf planes (L2/L3-hot, 16B coalesced)
        short8 afh[4], afl[4];
#pragma unroll
        for (int s16 = 0; s16 < 4; ++s16) {
            int gk = (k0 >> 3) + 2 * s16 + lk;
            afh[s16] = *(const short8*)&Yh[gk * 512 + am * 8];
            afl[s16] = *(const short8*)&Yl[gk * 512 + am * 8];
        }
        // stage B (hi only) into dbuf half
#pragma unroll
        for (int s = 0; s < 4; ++s) {
            int off = 4 * sj + 16 * s;
            int idx = sr * 64 + (((off >> 3) ^ (sr & 7)) * 8 + (off & 7));
            float fb[4] = {bbuf[slot][s].x, bbuf[slot][s].y, bbuf[slot][s].z, bbuf[slot][s].w};
            ushort4 h4;
            ushort* hp = (ushort*)&h4;
#pragma unroll
            for (int i = 0; i < 4; ++i) hp[i] = f2bf(fb[i]);
            *(ushort4*)&sh.g3.Bh[par][idx] = h4;
        }
        barrier_nodrain();  // this half's writes visible; prev-half reads drained (lgkm)
#pragma unroll
        for (int s16 = 0; s16 < 4; ++s16) {
            int gk = 2 * s16 + lk;
            int bi = bn * 64 + ((gk ^ (bn & 7)) * 8);
            short8 bh = *(const short8*)&sh.g3.Bh[par][bi];
            acc = mfma_bf16(afh[s16], bh, acc);
            acc = mfma_bf16(afl[s16], bh, acc);
        }
    }
    float* Cp = C + (size_t)ks * TILE;
    const int colg = n0 + tn * 32 + (l & 31);
#pragma unroll
    for (int r = 0; r < 16; ++r) {
        int row = (r & 3) + 8 * (r >> 2) + 4 * lk + tm * 32;
        Cp[row * 4096 + colg] = acc[r];
    }
}

// ---------------- phase-2: T = sum slabs; T = prod_j (I + a^(2^j) G_j) T; Ybf
__device__ void solve_body(SharedU& sh, const float* __restrict__ P1, const float* __restrict__ Gp,
                           const float* __restrict__ lam, const float* __restrict__ gam,
                           ushort* __restrict__ Yh, ushort* __restrict__ Yl, int bid, int t) {
    const int c0 = bid * 4;
    {  // slab pre-reduction: 4 groups x 4 slabs
        const int r = t & 63, sg = t >> 6;
        float4 a = {0.f, 0.f, 0.f, 0.f};
#pragma unroll
        for (int s = 0; s < 4; ++s) {
            const float4 v = *(const float4*)&P1[(size_t)(sg * 4 + s) * TILE + (size_t)r * 4096 + c0];
            a.x += v.x; a.y += v.y; a.z += v.z; a.w += v.w;
        }
        *(float4*)&sh.s.Tp[sg][r][0] = a;
    }
    barrier_nodrain();
    if (t < 64) {
        const int r = t;
        float4 a0 = *(const float4*)&sh.s.Tp[0][r][0];
        float4 a1 = *(const float4*)&sh.s.Tp[1][r][0];
        float4 a2 = *(const float4*)&sh.s.Tp[2][r][0];
        float4 a3 = *(const float4*)&sh.s.Tp[3][r][0];
        sh.s.T[r][0] = a0.x + a1.x + a2.x + a3.x;
        sh.s.T[r][1] = a0.y + a1.y + a2.y + a3.y;
        sh.s.T[r][2] = a0.z + a1.z + a2.z + a3.z;
        sh.s.T[r][3] = a0.w + a1.w + a2.w + a3.w;
    }
    barrier_nodrain();
    const int r = t >> 2, c = t & 3;
    float ap = gam[0] * lam[c0 + c];
    for (int j = 0; j < 5; ++j) {
        for (int e = t; e < 4096; e += 256) sh.s.Gs[e >> 6][e & 63] = Gp[j * 4096 + e];
        barrier_nodrain();
        float u = 0.f;
#pragma unroll 8
        for (int k = 0; k < 64; ++k) u += sh.s.Gs[r][k] * sh.s.T[k][c];
        barrier_nodrain();
        sh.s.T[r][c] += ap * u;
        ap = ap * ap;
        // next j's staging barrier (lgkm-drained) orders this write before the next reads
    }
    // epilogue: own cell -> Ybf hi/lo planes in MFMA-fragment layout
    const float v = sh.s.T[r][c];
    const ushort h = f2bf(v);
    const int col = c0 + c;
    const int idx = (col >> 3) * 512 + r * 8 + (col & 7);
    Yh[idx] = h;
    Yl[idx] = f2bf(v - bf2f(h));
}

// ---------------- fused kernel (plain launch + ws grid barriers) ------------
__global__ __launch_bounds__(256, 4) void fused_kernel(
    const float* __restrict__ X, const float* __restrict__ F,
    const float* __restrict__ Qs, const float* __restrict__ lam,
    const float* __restrict__ gam, float* __restrict__ Z,
    float* __restrict__ P1, float* __restrict__ P2, float* __restrict__ Gp,
    ushort* __restrict__ Yh, ushort* __restrict__ Yl, uint* bar) {
    __shared__ SharedU sh;
    const int b = blockIdx.x, t = threadIdx.x;

    // phase 1: gemm1; block 0 does prep first, then tile 0 (prep ~2 us, hidden-ish)
    if (b == 0) {
        prep_body(sh, F, Gp);
        gemm_lds(sh, X, Qs, P1, 0, t);
    } else {
        gemm_lds(sh, X, Qs, P1, b, t);
    }
    grid_barrier(bar, 0);

    // phase 2: fused slab-reduce + Neumann solve + Ybf emit
    solve_body(sh, P1, Gp, lam, gam, Yh, Yl, b, t);
    grid_barrier(bar, 1);

    // phase 3: gemm2 (A-frags direct from Ybf)
    gemm_direct(sh, Yh, Yl, Qs, P2, b, t);
    grid_barrier(bar, 2);

    // phase 4: Z = sum of KSPLIT P2 slabs (1 float/thread, grid == |Z|)
    const int gi = b * 256 + t;
    float a = 0.f;
#pragma unroll
    for (int s = 0; s < KSPLIT; ++s) a += P2[(size_t)s * TILE + gi];
    Z[gi] = a;
}

extern "C" void kernel_launch(void* const* d_in, const int* in_sizes, int n_in,
                              void* d_out, int out_size, void* d_ws, size_t ws_size,
                              hipStream_t stream) {
    const float* X     = (const float*)d_in[0];
    const float* F     = (const float*)d_in[1];
    const float* Qs    = (const float*)d_in[2];
    const float* lam   = (const float*)d_in[3];
    const float* gamma = (const float*)d_in[4];
    float* Z = (float*)d_out;

    float* P1 = (float*)d_ws;                    // 16 MB partial slabs (gemm1)
    float* P2 = P1 + (size_t)KSPLIT * TILE;      // 16 MB partial slabs (gemm2)
    float* Gp = P2 + (size_t)KSPLIT * TILE;      // 80 KB: G, G^2, G^4, G^8, G^16
    ushort* Yh = (ushort*)(Gp + 5 * 4096);       // 512 KB Y hi plane (fragment layout)
    ushort* Yl = Yh + TILE;                      // 512 KB Y lo plane
    uint* bar  = (uint*)(Yl + TILE);             // 3 single-use barrier slots

    hipMemsetAsync(bar, 0, 2048, stream);        // zero barrier slots (every replay)
    fused_kernel<<<NBLK, 256, 0, stream>>>(X, F, Qs, lam, gamma, Z,
                                           P1, P2, Gp, Yh, Yl, bar);
}

// Round 6
// 160.492 us; speedup vs baseline: 2.5488x; 2.5488x over previous
//
#include <hip/hip_runtime.h>
#include <math.h>

// Z = Q_F (D * (Q_F^T X Q_S)) Q_S^T  ==  per-column solve (I - g*lam_j*G) y_j = (X Q_S)_j ; Z = Y Q_S^T
// (I - aG)^-1 = prod_{j=0..4} (I + a^(2^j) G^(2^j))  (exact 31-term Neumann sum; rho <= 0.76)
// GEMMs: bf16 MFMA, A = hi+lo split (2 products), B = bf16 (2^-9 rel, OK vs 0.099 threshold).
//
// R6 == R5 resubmitted verbatim (R5 bench was an infra failure: "container failed twice";
// no kernel signal). Rationale recap:
//  R4 evidence: fused single-kernel ran correct but 330 us -- ~230 us in 3 software grid
//  barriers (same-line device-scope RMW serialization + L2-invalidating fences + lockstep).
//  -> back to the R2 multi-kernel skeleton (155 us best), keeping R4-verified components:
//  - solve fused with slab-reduce; epilogue emits Y directly as bf16 hi/lo planes in
//    MFMA-fragment layout (Ybf)  [R4-verified mapping]
//  - gemm2 = gemm_direct: A-frags register-direct from Ybf; LDS = B dbuf only (16 KB),
//    ONE nodrain barrier/step  [R4-verified]
//  - KSPLIT 16->32 with plain slab stores (no atomics): 2048 blocks/gemm, per-block chain
//    halves (2 K-steps of 64), B panel fully register-prefetched up-front.
// Dispatches: gemm1(+prep) -> solve -> gemm2 -> reduce2  (4 vs R2's 5).

typedef short short8 __attribute__((ext_vector_type(8)));
typedef float floatx16 __attribute__((ext_vector_type(16)));

#define KSPLIT 32
#define KCHUNK 128  // 4096 / KSPLIT, 2 steps of 64
constexpr int Mdim = 64;
constexpr int Ndim = 4096;
constexpr int TILE = Mdim * Ndim;  // 262144 floats = 1 MB

__device__ inline ushort f2bf(float f) {
    uint u = __float_as_uint(f);
    u += 0x7fff + ((u >> 16) & 1);  // RNE
    return (ushort)(u >> 16);
}
__device__ inline float bf2f(ushort h) { return __uint_as_float(((uint)h) << 16); }

__device__ inline floatx16 mfma_bf16(short8 a, short8 b, floatx16 c) {
    return __builtin_amdgcn_mfma_f32_32x32x16_bf16(a, b, c, 0, 0, 0);
}

// LDS plane layout (bf16, 64x64 tile): elem (r,k) at r*64 + ((k>>3)^(r&7))*8 + (k&7).
union SharedG1 {
    struct { ushort Ah[4096], Al[4096], Bh[4096]; } g;     // gemm1 (24 KB)
    struct { ushort planes[2][4096]; float red[256]; } p;  // prep (17 KB)
};

// Workgroup barrier WITHOUT vmcnt drain: LDS visibility only needs lgkmcnt(0).
__device__ inline void barrier_nodrain() {
    asm volatile("s_waitcnt lgkmcnt(0)" ::: "memory");
    __builtin_amdgcn_s_barrier();
    __builtin_amdgcn_sched_barrier(0);
}

// ---------------- prep body: G, G^2, G^4, G^8, G^16 (one block) -------------
__device__ void prep_body(SharedG1& sh, const float* __restrict__ F, float* __restrict__ Gout) {
    const int t = threadIdx.x;
    const int l = t & 63, w = t >> 6;
    const int tm = w & 1, tn = w >> 1;
    const int am = tm * 32 + (l & 31);
    const int bn = tn * 32 + (l & 31);
    const int lk = l >> 5;
    ushort* Ph = sh.p.planes[0];
    ushort* Pl = sh.p.planes[1];
    float* red = sh.p.red;

    {  // load F rows from global, scatter transposed into planes: P[c][k] = F[k][c]
        const int r = t >> 2, c0 = (t & 3) * 16;
#pragma unroll
        for (int q = 0; q < 4; ++q) {
            float4 v = *(const float4*)&F[r * 64 + c0 + 4 * q];
            float fa[4] = {v.x, v.y, v.z, v.w};
#pragma unroll
            for (int i = 0; i < 4; ++i) {
                int c = c0 + 4 * q + i;
                ushort h = f2bf(fa[i]);
                int idx = c * 64 + (((r >> 3) ^ (c & 7)) * 8) + (r & 7);
                Ph[idx] = h;
                Pl[idx] = f2bf(fa[i] - bf2f(h));
            }
        }
    }
    barrier_nodrain();
    floatx16 acc;
    for (int i = 0; i < 16; ++i) acc[i] = 0.f;
    for (int s16 = 0; s16 < 4; ++s16) {
        int gk = 2 * s16 + lk;
        int ai = am * 64 + ((gk ^ (am & 7)) * 8);
        int bi = bn * 64 + ((gk ^ (bn & 7)) * 8);
        short8 ah = *(const short8*)&Ph[ai];
        short8 al = *(const short8*)&Pl[ai];
        short8 bh = *(const short8*)&Ph[bi];
        short8 bl = *(const short8*)&Pl[bi];
        acc = mfma_bf16(ah, bh, acc);
        acc = mfma_bf16(al, bh, acc);
        acc = mfma_bf16(ah, bl, acc);
    }
    float ss = 0.f;
    for (int r = 0; r < 16; ++r) ss += acc[r] * acc[r];
    red[t] = ss;
    barrier_nodrain();
    for (int off = 128; off > 0; off >>= 1) {
        if (t < off) red[t] += red[t + off];
        barrier_nodrain();
    }
    const float inv = 1.0f / (sqrtf(red[0]) + 1e-12f);
    for (int r = 0; r < 16; ++r) {
        int row = (r & 3) + 8 * (r >> 2) + 4 * lk + tm * 32;
        int col = tn * 32 + (l & 31);
        float v = acc[r] * inv;
        Gout[row * 64 + col] = v;
        ushort h = f2bf(v);
        int idx = row * 64 + (((col >> 3) ^ (row & 7)) * 8 + (col & 7));
        Ph[idx] = h;
        Pl[idx] = f2bf(v - bf2f(h));
    }
    for (int j = 1; j < 5; ++j) {
        barrier_nodrain();
        floatx16 a2;
        for (int i = 0; i < 16; ++i) a2[i] = 0.f;
        for (int s16 = 0; s16 < 4; ++s16) {
            int gk = 2 * s16 + lk;
            int ai = am * 64 + ((gk ^ (am & 7)) * 8);
            int bi = bn * 64 + ((gk ^ (bn & 7)) * 8);
            short8 ah = *(const short8*)&Ph[ai];
            short8 al = *(const short8*)&Pl[ai];
            short8 bh = *(const short8*)&Ph[bi];
            short8 bl = *(const short8*)&Pl[bi];
            a2 = mfma_bf16(ah, bh, a2);
            a2 = mfma_bf16(al, bh, a2);
            a2 = mfma_bf16(ah, bl, a2);
        }
        barrier_nodrain();
        for (int r = 0; r < 16; ++r) {
            int row = (r & 3) + 8 * (r >> 2) + 4 * lk + tm * 32;
            int col = tn * 32 + (l & 31);
            float v = a2[r];
            Gout[j * 4096 + row * 64 + col] = v;
            ushort h = f2bf(v);
            int idx = row * 64 + (((col >> 3) ^ (row & 7)) * 8 + (col & 7));
            Ph[idx] = h;
            Pl[idx] = f2bf(v - bf2f(h));
        }
    }
}

// B-panel register load for one 64-k step.
template <bool TB>
__device__ inline void load_b(float4 (&dst)[4], const float* __restrict__ Bm,
                              int n0, int kk, int sr, int sj, int nq, int kr2) {
    if constexpr (TB) {
#pragma unroll
        for (int s = 0; s < 4; ++s)
            dst[s] = *(const float4*)&Bm[(size_t)(n0 + sr) * 4096 + kk + 4 * sj + 16 * s];
    } else {
#pragma unroll
        for (int s = 0; s < 2; ++s) {
            dst[2 * s + 0] = *(const float4*)&Bm[(size_t)(kk + kr2 + 32 * s) * 4096 + n0 + 4 * nq];
            dst[2 * s + 1] = *(const float4*)&Bm[(size_t)(kk + kr2 + 1 + 32 * s) * 4096 + n0 + 4 * nq];
        }
    }
}

// ---------------- gemm1: P1[ks] tile = X-chunk @ Qs-chunk (+ prep, block 0) -
// Both K-steps' B panels register-loaded up-front (full MLP burst); A (L2-hot)
// loaded in-step; hi+lo A split; nodrain barriers; slab stores (no atomics).
__global__ __launch_bounds__(256, 4) void gemm1_kernel(const float* __restrict__ A,
                                                       const float* __restrict__ Bm,
                                                       float* __restrict__ C,
                                                       const float* __restrict__ F,
                                                       float* __restrict__ Gp) {
    __shared__ SharedG1 sh;
    const int bid = blockIdx.x;
    if (bid == 0) { prep_body(sh, F, Gp); return; }
    const int b = bid - 1;
    const int n0 = (b & 63) * 64;
    const int ks = b >> 6;
    const int kb = ks * KCHUNK;
    const int t = threadIdx.x;
    const int l = t & 63, w = t >> 6;
    const int tm = w & 1, tn = w >> 1;
    const int am = tm * 32 + (l & 31);
    const int bn = tn * 32 + (l & 31);
    const int lk = l >> 5;
    const int sr = t >> 2, sj = t & 3;          // row-staging map
    const int nq = t & 15, kr2 = 2 * (t >> 4);  // transpose-staging map

    floatx16 acc;
    for (int i = 0; i < 16; ++i) acc[i] = 0.f;

    float4 bbuf[2][4];
    load_b<false>(bbuf[0], Bm, n0, kb, sr, sj, nq, kr2);
    load_b<false>(bbuf[1], Bm, n0, kb + 64, sr, sj, nq, kr2);

#pragma unroll
    for (int step = 0; step < KCHUNK / 64; ++step) {
        const int k0 = kb + step * 64;
        // A loads for this step (L2-hot, short latency)
        float4 av[4];
#pragma unroll
        for (int s = 0; s < 4; ++s)
            av[s] = *(const float4*)&A[sr * 4096 + k0 + 4 * sj + 16 * s];
        barrier_nodrain();  // previous step's frag ds_reads done (lgkm only; vmem in flight)
        // stage B (hi only); counted vmcnt inserted at first bbuf[step] use
#pragma unroll
        for (int s = 0; s < 2; ++s) {
            int k = kr2 + 32 * s;
            float fa[4] = {bbuf[step][2 * s].x, bbuf[step][2 * s].y, bbuf[step][2 * s].z, bbuf[step][2 * s].w};
            float fb[4] = {bbuf[step][2 * s + 1].x, bbuf[step][2 * s + 1].y, bbuf[step][2 * s + 1].z, bbuf[step][2 * s + 1].w};
#pragma unroll
            for (int i = 0; i < 4; ++i) {
                int n = 4 * nq + i;
                int idx = n * 64 + (((k >> 3) ^ (n & 7)) * 8 + (k & 7));
                ushort2 hp2;
                hp2.x = f2bf(fa[i]);
                hp2.y = f2bf(fb[i]);
                *(ushort2*)&sh.g.Bh[idx] = hp2;
            }
        }
        // stage A (hi + lo)
#pragma unroll
        for (int s = 0; s < 4; ++s) {
            int off = 4 * sj + 16 * s;
            int idx = sr * 64 + (((off >> 3) ^ (sr & 7)) * 8 + (off & 7));
            float fa[4] = {av[s].x, av[s].y, av[s].z, av[s].w};
            ushort4 h4, l4;
            ushort* hp = (ushort*)&h4; ushort* lp = (ushort*)&l4;
#pragma unroll
            for (int i = 0; i < 4; ++i) {
                ushort h = f2bf(fa[i]);
                hp[i] = h; lp[i] = f2bf(fa[i] - bf2f(h));
            }
            *(ushort4*)&sh.g.Ah[idx] = h4;
            *(ushort4*)&sh.g.Al[idx] = l4;
        }
        barrier_nodrain();  // staged planes visible to all waves
#pragma unroll
        for (int s16 = 0; s16 < 4; ++s16) {
            int gk = 2 * s16 + lk;
            int ai = am * 64 + ((gk ^ (am & 7)) * 8);
            int bi = bn * 64 + ((gk ^ (bn & 7)) * 8);
            short8 ah = *(const short8*)&sh.g.Ah[ai];
            short8 al = *(const short8*)&sh.g.Al[ai];
            short8 bh = *(const short8*)&sh.g.Bh[bi];
            acc = mfma_bf16(ah, bh, acc);
            acc = mfma_bf16(al, bh, acc);
        }
    }
    float* Cp = C + (size_t)ks * TILE;
    const int colg = n0 + tn * 32 + (l & 31);
#pragma unroll
    for (int r = 0; r < 16; ++r) {
        int row = (r & 3) + 8 * (r >> 2) + 4 * lk + tm * 32;
        Cp[row * 4096 + colg] = acc[r];
    }
}

// ---------------- solve: T = sum slabs; Neumann; emit Ybf hi/lo planes ------
// 256 blocks x 16 columns. Slab-reduce fused in (reads P1 directly, no W buffer).
// Epilogue writes Y as bf16 hi/lo planes in MFMA-fragment layout [R4-verified]:
// elem (r, col) at (col>>3)*512 + r*8 + (col&7).
__global__ __launch_bounds__(256) void solve_kernel(const float* __restrict__ P1,
                                                    const float* __restrict__ Gp,
                                                    const float* __restrict__ lam,
                                                    const float* __restrict__ gammap,
                                                    ushort* __restrict__ Yh,
                                                    ushort* __restrict__ Yl) {
    __shared__ float Gs[64][68];
    __shared__ float T[64][17];
    const int t = threadIdx.x;
    const int c0 = blockIdx.x * 16;
    {  // fused slab reduction: thread (r, q) sums KSPLIT slabs for cols 4q..4q+3
        const int r = t >> 2, q = t & 3;
        float4 a = {0.f, 0.f, 0.f, 0.f};
        for (int s = 0; s < KSPLIT; ++s) {
            const float4 v = *(const float4*)&P1[(size_t)s * TILE + (size_t)r * 4096 + c0 + 4 * q];
            a.x += v.x; a.y += v.y; a.z += v.z; a.w += v.w;
        }
        T[r][4 * q + 0] = a.x;
        T[r][4 * q + 1] = a.y;
        T[r][4 * q + 2] = a.z;
        T[r][4 * q + 3] = a.w;
    }
    const int tx = t & 15;
    const int r4 = (t >> 4) * 4;
    const float a0 = gammap[0] * lam[c0 + tx];
    float s = a0;
    for (int j = 0; j < 5; ++j) {
        __syncthreads();
        for (int e = t; e < 4096; e += 256) Gs[e >> 6][e & 63] = Gp[j * 4096 + e];
        __syncthreads();
        float u0 = 0.f, u1 = 0.f, u2 = 0.f, u3 = 0.f;
#pragma unroll 8
        for (int k = 0; k < 64; ++k) {
            const float tv = T[k][tx];
            const float4 g = *(const float4*)&Gs[k][r4];
            u0 += g.x * tv; u1 += g.y * tv; u2 += g.z * tv; u3 += g.w * tv;
        }
        __syncthreads();
        T[r4 + 0][tx] += s * u0;
        T[r4 + 1][tx] += s * u1;
        T[r4 + 2][tx] += s * u2;
        T[r4 + 3][tx] += s * u3;
        s = s * s;
    }
    __syncthreads();
    for (int e = t; e < 1024; e += 256) {
        const int r = e >> 4, cc = e & 15, col = c0 + cc;
        const float v = T[r][cc];
        const ushort h = f2bf(v);
        const int idx = (col >> 3) * 512 + r * 8 + (col & 7);
        Yh[idx] = h;
        Yl[idx] = f2bf(v - bf2f(h));
    }
}

// ---------------- gemm2: P2[ks] tile = Ybf-chunk @ Qs^T-chunk ---------------
// A-frags register-direct from Ybf planes (no A staging); LDS = B dbuf only
// (16 KB); ONE nodrain barrier/step; B up-front.
__global__ __launch_bounds__(256, 4) void gemm2_kernel(const ushort* __restrict__ Yh,
                                                       const ushort* __restrict__ Yl,
                                                       const float* __restrict__ Bm,
                                                       float* __restrict__ C) {
    __shared__ ushort Bhs[2][4096];
    const int b = blockIdx.x;
    const int n0 = (b & 63) * 64;
    const int ks = b >> 6;
    const int kb = ks * KCHUNK;
    const int t = threadIdx.x;
    const int l = t & 63, w = t >> 6;
    const int tm = w & 1, tn = w >> 1;
    const int am = tm * 32 + (l & 31);
    const int bn = tn * 32 + (l & 31);
    const int lk = l >> 5;
    const int sr = t >> 2, sj = t & 3;  // row-staging map (TB=true)

    floatx16 acc;
    for (int i = 0; i < 16; ++i) acc[i] = 0.f;

    float4 bbuf[2][4];
    load_b<true>(bbuf[0], Bm, n0, kb, sr, sj, 0, 0);
    load_b<true>(bbuf[1], Bm, n0, kb + 64, sr, sj, 0, 0);

#pragma unroll
    for (int step = 0; step < KCHUNK / 64; ++step) {
        const int k0 = kb + step * 64;
        const int par = step & 1;
        // A frags direct from Ybf planes (L2/L3-hot, 16B coalesced)
        short8 afh[4], afl[4];
#pragma unroll
        for (int s16 = 0; s16 < 4; ++s16) {
            int gk = (k0 >> 3) + 2 * s16 + lk;
            afh[s16] = *(const short8*)&Yh[gk * 512 + am * 8];
            afl[s16] = *(const short8*)&Yl[gk * 512 + am * 8];
        }
        // stage B (hi only) into dbuf half; counted vmcnt at first bbuf[step] use
#pragma unroll
        for (int s = 0; s < 4; ++s) {
            int off = 4 * sj + 16 * s;
            int idx = sr * 64 + (((off >> 3) ^ (sr & 7)) * 8 + (off & 7));
            float fb[4] = {bbuf[step][s].x, bbuf[step][s].y, bbuf[step][s].z, bbuf[step][s].w};
            ushort4 h4;
            ushort* hp = (ushort*)&h4;
#pragma unroll
            for (int i = 0; i < 4; ++i) hp[i] = f2bf(fb[i]);
            *(ushort4*)&Bhs[par][idx] = h4;
        }
        barrier_nodrain();  // this half's writes visible; prev-half reads drained (lgkm)
#pragma unroll
        for (int s16 = 0; s16 < 4; ++s16) {
            int gk = 2 * s16 + lk;
            int bi = bn * 64 + ((gk ^ (bn & 7)) * 8);
            short8 bh = *(const short8*)&Bhs[par][bi];
            acc = mfma_bf16(afh[s16], bh, acc);
            acc = mfma_bf16(afl[s16], bh, acc);
        }
    }
    float* Cp = C + (size_t)ks * TILE;
    const int colg = n0 + tn * 32 + (l & 31);
#pragma unroll
    for (int r = 0; r < 16; ++r) {
        int row = (r & 3) + 8 * (r >> 2) + 4 * lk + tm * 32;
        Cp[row * 4096 + colg] = acc[r];
    }
}

// ---------------- reduce2: Z = sum of KSPLIT P2 slabs -----------------------
__global__ __launch_bounds__(256) void reduce_kernel(const float* __restrict__ P,
                                                     float* __restrict__ out) {
    const int i = blockIdx.x * 256 + threadIdx.x;  // float4 index, 65536 total
    float4 a = {0.f, 0.f, 0.f, 0.f};
#pragma unroll
    for (int s = 0; s < KSPLIT; ++s) {
        const float4 v = *(const float4*)&P[(size_t)s * TILE + 4 * i];
        a.x += v.x; a.y += v.y; a.z += v.z; a.w += v.w;
    }
    *(float4*)&out[4 * i] = a;
}

extern "C" void kernel_launch(void* const* d_in, const int* in_sizes, int n_in,
                              void* d_out, int out_size, void* d_ws, size_t ws_size,
                              hipStream_t stream) {
    const float* X     = (const float*)d_in[0];
    const float* F     = (const float*)d_in[1];
    const float* Qs    = (const float*)d_in[2];
    const float* lam   = (const float*)d_in[3];
    const float* gamma = (const float*)d_in[4];
    float* Z = (float*)d_out;

    float* P1 = (float*)d_ws;                    // 32 MB partial slabs (gemm1)
    float* P2 = P1 + (size_t)KSPLIT * TILE;      // 32 MB partial slabs (gemm2)
    float* Gp = P2 + (size_t)KSPLIT * TILE;      // 80 KB: G, G^2, G^4, G^8, G^16
    ushort* Yh = (ushort*)(Gp + 5 * 4096);       // 512 KB Y hi plane (fragment layout)
    ushort* Yl = Yh + TILE;                      // 512 KB Y lo plane

    gemm1_kernel<<<64 * KSPLIT + 1, 256, 0, stream>>>(X, Qs, P1, F, Gp);
    solve_kernel<<<Ndim / 16, 256, 0, stream>>>(P1, Gp, lam, gamma, Yh, Yl);
    gemm2_kernel<<<64 * KSPLIT, 256, 0, stream>>>(Yh, Yl, Qs, P2);
    reduce_kernel<<<256, 256, 0, stream>>>(P2, Z);
}